// Round 4
// baseline (416.108 us; speedup 1.0000x reference)
//
#include <hip/hip_runtime.h>

#define D 128

typedef __attribute__((ext_vector_type(8))) short bf16x8;
typedef __attribute__((ext_vector_type(4))) float f32x4;

__device__ __forceinline__ unsigned short f2b(float v) {
    unsigned u = __float_as_uint(v);
    unsigned r = u + 0x7fffu + ((u >> 16) & 1u);   // RNE, inputs never NaN
    return (unsigned short)(r >> 16);
}
__device__ __forceinline__ float b2f(unsigned short h) {
    return __uint_as_float(((unsigned)h) << 16);
}

// ---------------- graph preprocessing ----------------

__global__ void hist_kernel(const int* __restrict__ dst, int* __restrict__ cnt, int E) {
    int e = blockIdx.x * blockDim.x + threadIdx.x;
    if (e < E) atomicAdd(&cnt[dst[e]], 1);
}

// ---- 3-phase multi-block exclusive scan over cnt[N] (chunk = 1024 elems/block) ----

__global__ __launch_bounds__(256) void scan_phase1(const int* __restrict__ cnt,
                                                   int* __restrict__ bsum, int N) {
    int t = threadIdx.x;
    int base = blockIdx.x * 1024 + t * 4;
    int s = 0;
    if (base + 4 <= N) {
        int4 v = *(const int4*)(cnt + base);
        s = v.x + v.y + v.z + v.w;
    } else {
        for (int k = 0; k < 4; ++k)
            if (base + k < N) s += cnt[base + k];
    }
    for (int off = 32; off; off >>= 1) s += __shfl_down(s, off);
    __shared__ int ws[4];
    if ((t & 63) == 0) ws[t >> 6] = s;
    __syncthreads();
    if (t == 0) bsum[blockIdx.x] = ws[0] + ws[1] + ws[2] + ws[3];
}

__global__ __launch_bounds__(256) void scan_phase2(const int* __restrict__ bsum,
                                                   int* __restrict__ boff,
                                                   int* __restrict__ rs, int nb, int N) {
    __shared__ int sh[256];
    int t = threadIdx.x;
    int v = (t < nb) ? bsum[t] : 0;
    sh[t] = v;
    __syncthreads();
    for (int off = 1; off < 256; off <<= 1) {
        int o = (t >= off) ? sh[t - off] : 0;
        __syncthreads();
        sh[t] += o;
        __syncthreads();
    }
    if (t < nb) boff[t] = sh[t] - v;
    if (t == 255) rs[N] = sh[255];  // == E
}

__global__ __launch_bounds__(256) void scan_phase3(const int* __restrict__ cnt,
                                                   const int* __restrict__ boff,
                                                   int* __restrict__ rs, int* __restrict__ fp,
                                                   float* __restrict__ dinv, int N) {
    __shared__ int tsum[256];
    int t = threadIdx.x;
    int base = blockIdx.x * 1024 + t * 4;
    int v[4];
    int s = 0;
    if (base + 4 <= N) {
        int4 vv = *(const int4*)(cnt + base);
        v[0] = vv.x; v[1] = vv.y; v[2] = vv.z; v[3] = vv.w;
        s = v[0] + v[1] + v[2] + v[3];
    } else {
        for (int k = 0; k < 4; ++k) {
            v[k] = (base + k < N) ? cnt[base + k] : 0;
            s += v[k];
        }
    }
    tsum[t] = s;
    __syncthreads();
    for (int off = 1; off < 256; off <<= 1) {
        int o = (t >= off) ? tsum[t - off] : 0;
        __syncthreads();
        tsum[t] += o;
        __syncthreads();
    }
    int run = boff[blockIdx.x] + tsum[t] - s;
#pragma unroll
    for (int k = 0; k < 4; ++k) {
        int idx = base + k;
        if (idx < N) {
            rs[idx] = run;
            fp[idx] = run;
            dinv[idx] = rsqrtf((float)(v[k] + 1));  // +1 self-loop
            run += v[k];
        }
    }
}

// CSR fill with packed (src, dinv[src]) payload -> one 8B scatter per edge
__global__ void fill_kernel(const int* __restrict__ src, const int* __restrict__ dst,
                            const float* __restrict__ dinv,
                            int* __restrict__ fp, int2* __restrict__ colvw, int E) {
    int e = blockIdx.x * blockDim.x + threadIdx.x;
    if (e < E) {
        int s = src[e];
        int slot = atomicAdd(&fp[dst[e]], 1);
        int2 p;
        p.x = s;
        p.y = __float_as_int(dinv[s]);
        colvw[slot] = p;
    }
}

// ---------------- fp32 -> bf16 hi/lo split (for GEMM A inputs) ----------------

__global__ void split4_kernel(const float4* __restrict__ X, ushort4* __restrict__ H,
                              ushort4* __restrict__ L, int n4) {
    int i = blockIdx.x * blockDim.x + threadIdx.x;
    if (i >= n4) return;
    float4 v = X[i];
    ushort4 h, l;
    h.x = f2b(v.x); l.x = f2b(v.x - b2f(h.x));
    h.y = f2b(v.y); l.y = f2b(v.y - b2f(h.y));
    h.z = f2b(v.z); l.z = f2b(v.z - b2f(h.z));
    h.w = f2b(v.w); l.w = f2b(v.w - b2f(h.w));
    H[i] = h;
    L[i] = l;
}

// three W[128,128] fp32 -> bf16-hi transposed [n][k], one launch
__global__ void wsplit3_kernel(const float* __restrict__ W1, const float* __restrict__ W2,
                               const float* __restrict__ Wq,
                               unsigned short* __restrict__ o1, unsigned short* __restrict__ o2,
                               unsigned short* __restrict__ oq) {
    int t = blockIdx.x * blockDim.x + threadIdx.x;  // 3 * 16384
    int which = t >> 14;
    int r = t & 16383;
    int n = r >> 7, k = r & 127;
    const float* W = (which == 0) ? W1 : (which == 1) ? W2 : Wq;
    unsigned short* o = (which == 0) ? o1 : (which == 1) ? o2 : oq;
    o[r] = f2b(W[k * D + n]);
}

// ---------------- MFMA GEMM: C[M,128] = (Ah+Al)[M,128] @ Wh[128,128] (+bias) ----------------
// 2-term bf16 split. Wave = 64 rows x 128 cols (4 m-tiles); W-frags loaded once
// per ks, reused x4. Block = 128 thr = 2 waves = 128 rows. Output bf16 (Cb) or
// fp32+bias (Cf).
__global__ __launch_bounds__(128) void mfma_gemm(const unsigned short* __restrict__ Ah,
                                                 const unsigned short* __restrict__ Al,
                                                 const unsigned short* __restrict__ Wth,
                                                 const float* __restrict__ bias,
                                                 unsigned short* __restrict__ Cb,
                                                 float* __restrict__ Cf, int M) {
    int lane = threadIdx.x & 63;
    int wave = threadIdx.x >> 6;
    int m64 = (blockIdx.x * 2 + wave) * 64;
    if (m64 >= M) return;
    int mrow = lane & 15;
    int quad = lane >> 4;
    int nmt = (M - m64) >> 4;  // M % 16 == 0 always
    if (nmt > 4) nmt = 4;

    f32x4 acc[4][8];
#pragma unroll
    for (int mt = 0; mt < 4; ++mt)
#pragma unroll
        for (int nt = 0; nt < 8; ++nt) acc[mt][nt] = (f32x4){0.f, 0.f, 0.f, 0.f};

    const unsigned short* abase = Ah + (size_t)(m64 + mrow) * D + quad * 8;
    const unsigned short* albase = Al + (size_t)(m64 + mrow) * D + quad * 8;

    if (nmt == 4) {
#pragma unroll
        for (int ks = 0; ks < 4; ++ks) {
            bf16x8 wf[8];
#pragma unroll
            for (int nt = 0; nt < 8; ++nt)
                wf[nt] = *(const bf16x8*)(Wth + (size_t)(nt * 16 + mrow) * D + ks * 32 + quad * 8);
#pragma unroll
            for (int mt = 0; mt < 4; ++mt) {
                bf16x8 a  = *(const bf16x8*)(abase  + (size_t)mt * 16 * D + ks * 32);
                bf16x8 al = *(const bf16x8*)(albase + (size_t)mt * 16 * D + ks * 32);
#pragma unroll
                for (int nt = 0; nt < 8; ++nt) {
                    acc[mt][nt] = __builtin_amdgcn_mfma_f32_16x16x32_bf16(a, wf[nt], acc[mt][nt], 0, 0, 0);
                    acc[mt][nt] = __builtin_amdgcn_mfma_f32_16x16x32_bf16(al, wf[nt], acc[mt][nt], 0, 0, 0);
                }
            }
        }
    } else {
        for (int ks = 0; ks < 4; ++ks) {
            bf16x8 wf[8];
#pragma unroll
            for (int nt = 0; nt < 8; ++nt)
                wf[nt] = *(const bf16x8*)(Wth + (size_t)(nt * 16 + mrow) * D + ks * 32 + quad * 8);
            for (int mt = 0; mt < nmt; ++mt) {
                bf16x8 a  = *(const bf16x8*)(abase  + (size_t)mt * 16 * D + ks * 32);
                bf16x8 al = *(const bf16x8*)(albase + (size_t)mt * 16 * D + ks * 32);
#pragma unroll
                for (int nt = 0; nt < 8; ++nt) {
                    acc[mt][nt] = __builtin_amdgcn_mfma_f32_16x16x32_bf16(a, wf[nt], acc[mt][nt], 0, 0, 0);
                    acc[mt][nt] = __builtin_amdgcn_mfma_f32_16x16x32_bf16(al, wf[nt], acc[mt][nt], 0, 0, 0);
                }
            }
        }
    }

    // C/D layout: col = lane&15, row = quad*4 + reg
    if (Cb) {
        for (int mt = 0; mt < nmt; ++mt) {
#pragma unroll
            for (int nt = 0; nt < 8; ++nt) {
                int col = nt * 16 + mrow;
#pragma unroll
                for (int r = 0; r < 4; ++r) {
                    int row = m64 + mt * 16 + quad * 4 + r;
                    Cb[(size_t)row * D + col] = f2b(acc[mt][nt][r]);
                }
            }
        }
    } else {
        for (int mt = 0; mt < nmt; ++mt) {
#pragma unroll
            for (int nt = 0; nt < 8; ++nt) {
                int col = nt * 16 + mrow;
                float bv = bias[col];
#pragma unroll
                for (int r = 0; r < 4; ++r) {
                    int row = m64 + mt * 16 + quad * 4 + r;
                    Cf[(size_t)row * D + col] = acc[mt][nt][r] + bv;
                }
            }
        }
    }
}

// ---------------- aggregation over bf16 rows ----------------
// O[i] = dinv[i] * sum_j w_j * T[j] + dinv[i]^2 * T[i] + b ; optional relu.
// T is bf16 [N,128]. mode 1: relu, write h1 as bf16 hi/lo. mode 0: write fp32.
__global__ __launch_bounds__(256) void aggregate(const unsigned short* __restrict__ Tb,
                                                 const int2* __restrict__ colvw,
                                                 const int* __restrict__ rs,
                                                 const float* __restrict__ dinv,
                                                 const float* __restrict__ bias,
                                                 float* __restrict__ Of,
                                                 unsigned short* __restrict__ Oh,
                                                 unsigned short* __restrict__ Ol,
                                                 int N, int mode) {
    int wave = threadIdx.x >> 6;
    int lane = threadIdx.x & 63;
    int i = blockIdx.x * 4 + wave;
    if (i >= N) return;

    const ushort2* T2 = (const ushort2*)Tb;
    int f = lane;  // ushort2 index within row (row = 64 ushort2 = 256B)

    int e0 = rs[i];
    int e1 = rs[i + 1];
    float ax = 0.f, ay = 0.f;

    for (int base = e0; base < e1; base += 64) {
        int cnt = e1 - base;
        if (cnt > 64) cnt = 64;
        int2 p = (lane < cnt) ? colvw[base + lane] : make_int2(0, 0);

        int t = 0;
        for (; t + 8 <= cnt; t += 8) {
            int jj[8];
            float ww[8];
#pragma unroll
            for (int k = 0; k < 8; ++k) {
                jj[k] = __shfl(p.x, t + k);
                ww[k] = __int_as_float(__shfl(p.y, t + k));
            }
            ushort2 rr[8];
#pragma unroll
            for (int k = 0; k < 8; ++k) rr[k] = T2[(size_t)jj[k] * 64 + f];
#pragma unroll
            for (int k = 0; k < 8; ++k) {
                ax = fmaf(ww[k], b2f(rr[k].x), ax);
                ay = fmaf(ww[k], b2f(rr[k].y), ay);
            }
        }
        for (; t < cnt; ++t) {
            int j = __shfl(p.x, t);
            float w = __int_as_float(__shfl(p.y, t));
            ushort2 r = T2[(size_t)j * 64 + f];
            ax = fmaf(w, b2f(r.x), ax);
            ay = fmaf(w, b2f(r.y), ay);
        }
    }

    float di = dinv[i];
    ushort2 selfr = T2[(size_t)i * 64 + f];
    float2 bv = ((const float2*)bias)[f];
    float rx = di * ax + di * di * b2f(selfr.x) + bv.x;
    float ry = di * ay + di * di * b2f(selfr.y) + bv.y;
    if (mode) {
        rx = fmaxf(rx, 0.f);
        ry = fmaxf(ry, 0.f);
        ushort2 h, l;
        h.x = f2b(rx); l.x = f2b(rx - b2f(h.x));
        h.y = f2b(ry); l.y = f2b(ry - b2f(h.y));
        ((ushort2*)Oh)[(size_t)i * 64 + f] = h;
        ((ushort2*)Ol)[(size_t)i * 64 + f] = l;
    } else {
        float2 res;
        res.x = rx;
        res.y = ry;
        ((float2*)Of)[(size_t)i * 64 + f] = res;
    }
}

// ---------------- launch ----------------

static inline char* carve(char*& w, size_t bytes) {
    char* p = w;
    w += (bytes + 255) & ~(size_t)255;
    return p;
}

extern "C" void kernel_launch(void* const* d_in, const int* in_sizes, int n_in,
                              void* d_out, int out_size, void* d_ws, size_t ws_size,
                              hipStream_t stream) {
    const float* x  = (const float*)d_in[0];
    const int*   ei = (const int*)d_in[1];
    const float* q  = (const float*)d_in[2];
    const float* W1 = (const float*)d_in[3];
    const float* b1 = (const float*)d_in[4];
    const float* W2 = (const float*)d_in[5];
    const float* b2 = (const float*)d_in[6];
    const float* Wq = (const float*)d_in[7];
    const float* bq = (const float*)d_in[8];

    int N  = in_sizes[0] / D;  // 50000
    int E  = in_sizes[1] / 2;  // 800000
    int MQ = in_sizes[2] / D;  // 20000

    const int* srcv = ei;
    const int* dstv = ei + E;

    char* w = (char*)d_ws;
    unsigned short* Cb   = (unsigned short*)carve(w, (size_t)N * D * 2);  // t1/t2 bf16
    unsigned short* Hb   = (unsigned short*)carve(w, (size_t)N * D * 2);  // A-hi (x -> h1 -> q)
    unsigned short* Lb   = (unsigned short*)carve(w, (size_t)N * D * 2);  // A-lo
    int2*           colvw= (int2*)carve(w, (size_t)E * 8);
    int*            cnt  = (int*)carve(w, (size_t)N * 4);
    int*            rs   = (int*)carve(w, (size_t)(N + 1) * 4);
    int*            fp   = (int*)carve(w, (size_t)N * 4);
    float*          dinv = (float*)carve(w, (size_t)N * 4);
    int*            bsum = (int*)carve(w, 256 * 4);
    int*            boff = (int*)carve(w, 256 * 4);
    unsigned short* Wth1 = (unsigned short*)carve(w, D * D * 2);
    unsigned short* Wth2 = (unsigned short*)carve(w, D * D * 2);
    unsigned short* Wthq = (unsigned short*)carve(w, D * D * 2);

    float* outq = (float*)d_out;
    float* outh = outq + (size_t)MQ * D;

    int nb = (N + 1023) / 1024;  // 49

    // graph preprocessing
    hipMemsetAsync(cnt, 0, (size_t)N * 4, stream);
    hist_kernel<<<(E + 255) / 256, 256, 0, stream>>>(dstv, cnt, E);
    scan_phase1<<<nb, 256, 0, stream>>>(cnt, bsum, N);
    scan_phase2<<<1, 256, 0, stream>>>(bsum, boff, rs, nb, N);
    scan_phase3<<<nb, 256, 0, stream>>>(cnt, boff, rs, fp, dinv, N);
    fill_kernel<<<(E + 255) / 256, 256, 0, stream>>>(srcv, dstv, dinv, fp, colvw, E);

    wsplit3_kernel<<<192, 256, 0, stream>>>(W1, W2, Wq, Wth1, Wth2, Wthq);

    // conv1: t1 = x@W1 (bf16) ; h1 = relu(agg(t1)+b1) -> bf16 hi/lo
    int n4x = N * D / 4;
    split4_kernel<<<(n4x + 255) / 256, 256, 0, stream>>>((const float4*)x, (ushort4*)Hb, (ushort4*)Lb, n4x);
    mfma_gemm<<<(N + 127) / 128, 128, 0, stream>>>(Hb, Lb, Wth1, nullptr, Cb, nullptr, N);
    aggregate<<<(N + 3) / 4, 256, 0, stream>>>(Cb, colvw, rs, dinv, b1, nullptr, Hb, Lb, N, 1);

    // conv2: t2 = h1@W2 (bf16) ; h2 = agg(t2)+b2 -> fp32 out
    mfma_gemm<<<(N + 127) / 128, 128, 0, stream>>>(Hb, Lb, Wth2, nullptr, Cb, nullptr, N);
    aggregate<<<(N + 3) / 4, 256, 0, stream>>>(Cb, colvw, rs, dinv, b2, outh, nullptr, nullptr, N, 0);

    // ques = q@Wq + bq (fp32 out)
    int n4q = MQ * D / 4;
    split4_kernel<<<(n4q + 255) / 256, 256, 0, stream>>>((const float4*)q, (ushort4*)Hb, (ushort4*)Lb, n4q);
    mfma_gemm<<<(MQ + 127) / 128, 128, 0, stream>>>(Hb, Lb, Wthq, bq, nullptr, outq, MQ);
}

// Round 5
// 389.524 us; speedup vs baseline: 1.0682x; 1.0682x over previous
//
#include <hip/hip_runtime.h>

#define D 128

typedef __attribute__((ext_vector_type(8))) short bf16x8;
typedef __attribute__((ext_vector_type(4))) float f32x4;

__device__ __forceinline__ unsigned short f2b(float v) {
    unsigned u = __float_as_uint(v);
    unsigned r = u + 0x7fffu + ((u >> 16) & 1u);   // RNE, inputs never NaN
    return (unsigned short)(r >> 16);
}
__device__ __forceinline__ float b2f(unsigned short h) {
    return __uint_as_float(((unsigned)h) << 16);
}

// ---------------- graph preprocessing ----------------

__global__ void hist_kernel(const int* __restrict__ dst, int* __restrict__ cnt, int E) {
    int e = blockIdx.x * blockDim.x + threadIdx.x;
    if (e < E) atomicAdd(&cnt[dst[e]], 1);
}

// ---- 3-phase multi-block exclusive scan over cnt[N] ----

__global__ __launch_bounds__(256) void scan_phase1(const int* __restrict__ cnt,
                                                   int* __restrict__ bsum, int N) {
    int t = threadIdx.x;
    int base = blockIdx.x * 1024 + t * 4;
    int s = 0;
    if (base + 4 <= N) {
        int4 v = *(const int4*)(cnt + base);
        s = v.x + v.y + v.z + v.w;
    } else {
        for (int k = 0; k < 4; ++k)
            if (base + k < N) s += cnt[base + k];
    }
    for (int off = 32; off; off >>= 1) s += __shfl_down(s, off);
    __shared__ int ws[4];
    if ((t & 63) == 0) ws[t >> 6] = s;
    __syncthreads();
    if (t == 0) bsum[blockIdx.x] = ws[0] + ws[1] + ws[2] + ws[3];
}

__global__ __launch_bounds__(256) void scan_phase2(const int* __restrict__ bsum,
                                                   int* __restrict__ boff,
                                                   int* __restrict__ rs, int nb, int N) {
    __shared__ int sh[256];
    int t = threadIdx.x;
    int v = (t < nb) ? bsum[t] : 0;
    sh[t] = v;
    __syncthreads();
    for (int off = 1; off < 256; off <<= 1) {
        int o = (t >= off) ? sh[t - off] : 0;
        __syncthreads();
        sh[t] += o;
        __syncthreads();
    }
    if (t < nb) boff[t] = sh[t] - v;
    if (t == 255) rs[N] = sh[255];  // == E
}

__global__ __launch_bounds__(256) void scan_phase3(const int* __restrict__ cnt,
                                                   const int* __restrict__ boff,
                                                   int* __restrict__ rs, int* __restrict__ fp,
                                                   float* __restrict__ dinv, int N) {
    __shared__ int tsum[256];
    int t = threadIdx.x;
    int base = blockIdx.x * 1024 + t * 4;
    int v[4];
    int s = 0;
    if (base + 4 <= N) {
        int4 vv = *(const int4*)(cnt + base);
        v[0] = vv.x; v[1] = vv.y; v[2] = vv.z; v[3] = vv.w;
        s = v[0] + v[1] + v[2] + v[3];
    } else {
        for (int k = 0; k < 4; ++k) {
            v[k] = (base + k < N) ? cnt[base + k] : 0;
            s += v[k];
        }
    }
    tsum[t] = s;
    __syncthreads();
    for (int off = 1; off < 256; off <<= 1) {
        int o = (t >= off) ? tsum[t - off] : 0;
        __syncthreads();
        tsum[t] += o;
        __syncthreads();
    }
    int run = boff[blockIdx.x] + tsum[t] - s;
#pragma unroll
    for (int k = 0; k < 4; ++k) {
        int idx = base + k;
        if (idx < N) {
            rs[idx] = run;
            fp[idx] = run;
            dinv[idx] = rsqrtf((float)(v[k] + 1));  // +1 self-loop
            run += v[k];
        }
    }
}

// CSR fill with packed (src, dinv[src]) payload -> one 8B scatter per edge
__global__ void fill_kernel(const int* __restrict__ src, const int* __restrict__ dst,
                            const float* __restrict__ dinv,
                            int* __restrict__ fp, int2* __restrict__ colvw, int E) {
    int e = blockIdx.x * blockDim.x + threadIdx.x;
    if (e < E) {
        int s = src[e];
        int slot = atomicAdd(&fp[dst[e]], 1);
        int2 p;
        p.x = s;
        p.y = __float_as_int(dinv[s]);
        colvw[slot] = p;
    }
}

// three W[128,128] fp32 -> bf16-hi transposed [n][k], one launch
__global__ void wsplit3_kernel(const float* __restrict__ W1, const float* __restrict__ W2,
                               const float* __restrict__ Wq,
                               unsigned short* __restrict__ o1, unsigned short* __restrict__ o2,
                               unsigned short* __restrict__ oq) {
    int t = blockIdx.x * blockDim.x + threadIdx.x;  // 3 * 16384
    int which = t >> 14;
    int r = t & 16383;
    int n = r >> 7, k = r & 127;
    const float* W = (which == 0) ? W1 : (which == 1) ? W2 : Wq;
    unsigned short* o = (which == 0) ? o1 : (which == 1) ? o2 : oq;
    o[r] = f2b(W[k * D + n]);
}

// ---------------- MFMA GEMM: C[M,128] = A[M,128] @ W[128,128] (+bias) ----------------
// A either fp32 (Af, split to bf16 hi/lo in-kernel) or prescaled bf16 hi/lo (Ah/Al).
// 2-term bf16-split product (A_hi*W_h + A_lo*W_h). OPERAND-SWAPPED mfma:
// mfma(w_frag, a_frag) -> D = C^T fragments: lane&15 = C-row, the 4 acc regs =
// 4 CONSECUTIVE C-cols (nt*16 + quad*4 + r). Epilogue: ushort4 / float4 stores,
// fully coalesced (32B/64B contiguous per row per instruction).
// Wave = 32 rows (2 m-tiles), block = 256 (4 waves = 128 rows).
__global__ __launch_bounds__(256) void mfma_gemm(const float* __restrict__ Af,
                                                 const unsigned short* __restrict__ Ah,
                                                 const unsigned short* __restrict__ Al,
                                                 const unsigned short* __restrict__ Wth,
                                                 const float* __restrict__ bias,
                                                 unsigned short* __restrict__ Cb,
                                                 float* __restrict__ Cf, int M) {
    int lane = threadIdx.x & 63;
    int wave = threadIdx.x >> 6;
    int m32 = (blockIdx.x * 4 + wave) * 32;
    if (m32 >= M) return;
    int mrow = lane & 15;
    int quad = lane >> 4;
    int nmt = (M - m32) >> 4;  // M % 16 == 0 always
    if (nmt > 2) nmt = 2;

    f32x4 acc[2][8];
#pragma unroll
    for (int mt = 0; mt < 2; ++mt)
#pragma unroll
        for (int nt = 0; nt < 8; ++nt) acc[mt][nt] = (f32x4){0.f, 0.f, 0.f, 0.f};

#pragma unroll
    for (int ks = 0; ks < 4; ++ks) {
        bf16x8 wf[8];
#pragma unroll
        for (int nt = 0; nt < 8; ++nt)
            wf[nt] = *(const bf16x8*)(Wth + (size_t)(nt * 16 + mrow) * D + ks * 32 + quad * 8);

        for (int mt = 0; mt < nmt; ++mt) {
            int arow = m32 + mt * 16 + mrow;
            bf16x8 ah, al;
            if (Af) {
                const float* ap = Af + (size_t)arow * D + ks * 32 + quad * 8;
                float4 v0 = *(const float4*)ap;
                float4 v1 = *(const float4*)(ap + 4);
                float vv[8] = {v0.x, v0.y, v0.z, v0.w, v1.x, v1.y, v1.z, v1.w};
#pragma unroll
                for (int j = 0; j < 8; ++j) {
                    unsigned short h = f2b(vv[j]);
                    ah[j] = (short)h;
                    al[j] = (short)f2b(vv[j] - b2f(h));
                }
            } else {
                const unsigned short* p = Ah + (size_t)arow * D + ks * 32 + quad * 8;
                const unsigned short* pl = Al + (size_t)arow * D + ks * 32 + quad * 8;
                ah = *(const bf16x8*)p;
                al = *(const bf16x8*)pl;
            }
#pragma unroll
            for (int nt = 0; nt < 8; ++nt) {
                acc[mt][nt] = __builtin_amdgcn_mfma_f32_16x16x32_bf16(wf[nt], ah, acc[mt][nt], 0, 0, 0);
                acc[mt][nt] = __builtin_amdgcn_mfma_f32_16x16x32_bf16(wf[nt], al, acc[mt][nt], 0, 0, 0);
            }
        }
    }

    // D^T layout: lane&15 = C-row (within m-tile), regs = cols nt*16+quad*4+{0..3}
    if (Cb) {
        for (int mt = 0; mt < nmt; ++mt) {
            int row = m32 + mt * 16 + mrow;
#pragma unroll
            for (int nt = 0; nt < 8; ++nt) {
                ushort4 o;
                o.x = f2b(acc[mt][nt][0]);
                o.y = f2b(acc[mt][nt][1]);
                o.z = f2b(acc[mt][nt][2]);
                o.w = f2b(acc[mt][nt][3]);
                *(ushort4*)(Cb + (size_t)row * D + nt * 16 + quad * 4) = o;
            }
        }
    } else {
        for (int mt = 0; mt < nmt; ++mt) {
            int row = m32 + mt * 16 + mrow;
#pragma unroll
            for (int nt = 0; nt < 8; ++nt) {
                float4 bv = ((const float4*)bias)[nt * 4 + quad];
                float4 o;
                o.x = acc[mt][nt][0] + bv.x;
                o.y = acc[mt][nt][1] + bv.y;
                o.z = acc[mt][nt][2] + bv.z;
                o.w = acc[mt][nt][3] + bv.w;
                *(float4*)(Cf + (size_t)row * D + nt * 16 + quad * 4) = o;
            }
        }
    }
}

// ---------------- aggregation over bf16 rows ----------------
// O[i] = dinv[i] * sum_j w_j * T[j] + dinv[i]^2 * T[i] + b ; optional relu.
// T is bf16 [N,128]. mode 1: relu, write h1 as bf16 hi/lo. mode 0: write fp32.
__global__ __launch_bounds__(256) void aggregate(const unsigned short* __restrict__ Tb,
                                                 const int2* __restrict__ colvw,
                                                 const int* __restrict__ rs,
                                                 const float* __restrict__ dinv,
                                                 const float* __restrict__ bias,
                                                 float* __restrict__ Of,
                                                 unsigned short* __restrict__ Oh,
                                                 unsigned short* __restrict__ Ol,
                                                 int N, int mode) {
    int wave = threadIdx.x >> 6;
    int lane = threadIdx.x & 63;
    int i = blockIdx.x * 4 + wave;
    if (i >= N) return;

    const ushort2* T2 = (const ushort2*)Tb;
    int f = lane;  // ushort2 index within row (row = 64 ushort2 = 256B)

    int e0 = rs[i];
    int e1 = rs[i + 1];
    float ax = 0.f, ay = 0.f;

    for (int base = e0; base < e1; base += 64) {
        int cnt = e1 - base;
        if (cnt > 64) cnt = 64;
        int2 p = (lane < cnt) ? colvw[base + lane] : make_int2(0, 0);

        int t = 0;
        for (; t + 8 <= cnt; t += 8) {
            int jj[8];
            float ww[8];
#pragma unroll
            for (int k = 0; k < 8; ++k) {
                jj[k] = __shfl(p.x, t + k);
                ww[k] = __int_as_float(__shfl(p.y, t + k));
            }
            ushort2 rr[8];
#pragma unroll
            for (int k = 0; k < 8; ++k) rr[k] = T2[(size_t)jj[k] * 64 + f];
#pragma unroll
            for (int k = 0; k < 8; ++k) {
                ax = fmaf(ww[k], b2f(rr[k].x), ax);
                ay = fmaf(ww[k], b2f(rr[k].y), ay);
            }
        }
        for (; t < cnt; ++t) {
            int j = __shfl(p.x, t);
            float w = __int_as_float(__shfl(p.y, t));
            ushort2 r = T2[(size_t)j * 64 + f];
            ax = fmaf(w, b2f(r.x), ax);
            ay = fmaf(w, b2f(r.y), ay);
        }
    }

    float di = dinv[i];
    ushort2 selfr = T2[(size_t)i * 64 + f];
    float2 bv = ((const float2*)bias)[f];
    float rx = di * ax + di * di * b2f(selfr.x) + bv.x;
    float ry = di * ay + di * di * b2f(selfr.y) + bv.y;
    if (mode) {
        rx = fmaxf(rx, 0.f);
        ry = fmaxf(ry, 0.f);
        ushort2 h, l;
        h.x = f2b(rx); l.x = f2b(rx - b2f(h.x));
        h.y = f2b(ry); l.y = f2b(ry - b2f(h.y));
        ((ushort2*)Oh)[(size_t)i * 64 + f] = h;
        ((ushort2*)Ol)[(size_t)i * 64 + f] = l;
    } else {
        float2 res;
        res.x = rx;
        res.y = ry;
        ((float2*)Of)[(size_t)i * 64 + f] = res;
    }
}

// ---------------- launch ----------------

static inline char* carve(char*& w, size_t bytes) {
    char* p = w;
    w += (bytes + 255) & ~(size_t)255;
    return p;
}

extern "C" void kernel_launch(void* const* d_in, const int* in_sizes, int n_in,
                              void* d_out, int out_size, void* d_ws, size_t ws_size,
                              hipStream_t stream) {
    const float* x  = (const float*)d_in[0];
    const int*   ei = (const int*)d_in[1];
    const float* q  = (const float*)d_in[2];
    const float* W1 = (const float*)d_in[3];
    const float* b1 = (const float*)d_in[4];
    const float* W2 = (const float*)d_in[5];
    const float* b2 = (const float*)d_in[6];
    const float* Wq = (const float*)d_in[7];
    const float* bq = (const float*)d_in[8];

    int N  = in_sizes[0] / D;  // 50000
    int E  = in_sizes[1] / 2;  // 800000
    int MQ = in_sizes[2] / D;  // 20000

    const int* srcv = ei;
    const int* dstv = ei + E;

    char* w = (char*)d_ws;
    unsigned short* Cb   = (unsigned short*)carve(w, (size_t)N * D * 2);  // t1/t2 bf16
    unsigned short* Hb   = (unsigned short*)carve(w, (size_t)N * D * 2);  // h1-hi
    unsigned short* Lb   = (unsigned short*)carve(w, (size_t)N * D * 2);  // h1-lo
    int2*           colvw= (int2*)carve(w, (size_t)E * 8);
    int*            cnt  = (int*)carve(w, (size_t)N * 4);
    int*            rs   = (int*)carve(w, (size_t)(N + 1) * 4);
    int*            fp   = (int*)carve(w, (size_t)N * 4);
    float*          dinv = (float*)carve(w, (size_t)N * 4);
    int*            bsum = (int*)carve(w, 256 * 4);
    int*            boff = (int*)carve(w, 256 * 4);
    unsigned short* Wth1 = (unsigned short*)carve(w, D * D * 2);
    unsigned short* Wth2 = (unsigned short*)carve(w, D * D * 2);
    unsigned short* Wthq = (unsigned short*)carve(w, D * D * 2);

    float* outq = (float*)d_out;
    float* outh = outq + (size_t)MQ * D;

    int nb = (N + 1023) / 1024;  // 49

    // graph preprocessing
    hipMemsetAsync(cnt, 0, (size_t)N * 4, stream);
    hist_kernel<<<(E + 255) / 256, 256, 0, stream>>>(dstv, cnt, E);
    scan_phase1<<<nb, 256, 0, stream>>>(cnt, bsum, N);
    scan_phase2<<<1, 256, 0, stream>>>(bsum, boff, rs, nb, N);
    scan_phase3<<<nb, 256, 0, stream>>>(cnt, boff, rs, fp, dinv, N);
    fill_kernel<<<(E + 255) / 256, 256, 0, stream>>>(srcv, dstv, dinv, fp, colvw, E);

    wsplit3_kernel<<<192, 256, 0, stream>>>(W1, W2, Wq, Wth1, Wth2, Wthq);

    // conv1: t1 = x@W1 (bf16, in-kernel split) ; h1 = relu(agg(t1)+b1) -> bf16 hi/lo
    mfma_gemm<<<(N + 127) / 128, 256, 0, stream>>>(x, nullptr, nullptr, Wth1, nullptr, Cb, nullptr, N);
    aggregate<<<(N + 3) / 4, 256, 0, stream>>>(Cb, colvw, rs, dinv, b1, nullptr, Hb, Lb, N, 1);

    // conv2: t2 = h1@W2 (bf16) ; h2 = agg(t2)+b2 -> fp32 out
    mfma_gemm<<<(N + 127) / 128, 256, 0, stream>>>(nullptr, Hb, Lb, Wth2, nullptr, Cb, nullptr, N);
    aggregate<<<(N + 3) / 4, 256, 0, stream>>>(Cb, colvw, rs, dinv, b2, outh, nullptr, nullptr, N, 0);

    // ques = q@Wq + bq (fp32 out, in-kernel split)
    mfma_gemm<<<(MQ + 127) / 128, 256, 0, stream>>>(q, nullptr, nullptr, Wthq, bq, nullptr, outq, MQ);
}